// Round 1
// baseline (1809.819 us; speedup 1.0000x reference)
//
#include <hip/hip_runtime.h>

#define BATCH 256
#define SEQ   128
#define EDIM  300
#define PDIM  200
#define BSTOK (BATCH * SEQ)

#define F_RELU  1
#define F_ACCUM 2

// ---------------------------------------------------------------------------
// Generic fp32 tiled GEMM: C[M,N] = A[M,K] * B (NN: B[K,N]; NT: B[N,K])
// 64x64 block tile, BK=16, 256 threads, 4x4 microtile per thread.
// Batched via blockIdx.z with element strides sA/sB/sC.
// flags: F_RELU (relu epilogue), F_ACCUM (C += result before relu)
// ---------------------------------------------------------------------------
template <bool BT>
__global__ __launch_bounds__(256) void gemm_kernel(
    const float* __restrict__ A, const float* __restrict__ Bm,
    float* __restrict__ C, int M, int N, int K, int lda, int ldb, int ldc,
    long long sA, long long sB, long long sC, int flags)
{
    // pad row stride to 68 floats (272B, 16B-aligned) -> b128 LDS reads, no conflicts
    __shared__ float As[16][68];
    __shared__ float Bs[16][68];

    const int bz = blockIdx.z;
    A  += (long long)bz * sA;
    Bm += (long long)bz * sB;
    C  += (long long)bz * sC;

    const int tid = threadIdx.x;
    const int bn = blockIdx.x * 64;
    const int bm = blockIdx.y * 64;
    const int tx = tid & 15;   // 16 cols of threads
    const int ty = tid >> 4;   // 16 rows of threads

    float acc[4][4] = {};

    for (int k0 = 0; k0 < K; k0 += 16) {
        // A tile: As[k][m] = A[bm+m, k0+k]
        {
            const int lk = tid & 15;
            const int m0 = tid >> 4;
            const int gk = k0 + lk;
            #pragma unroll
            for (int i = 0; i < 4; i++) {
                const int m = m0 + i * 16;
                const int gm = bm + m;
                float v = 0.f;
                if (gm < M && gk < K) v = A[(long long)gm * lda + gk];
                As[lk][m] = v;
            }
        }
        if (!BT) {
            // Bs[k][n] = B[k0+k, bn+n]
            const int ln = tid & 63;
            const int kb = tid >> 6;
            const int gn = bn + ln;
            #pragma unroll
            for (int i = 0; i < 4; i++) {
                const int k = kb + i * 4;
                const int gk = k0 + k;
                float v = 0.f;
                if (gk < K && gn < N) v = Bm[(long long)gk * ldb + gn];
                Bs[k][ln] = v;
            }
        } else {
            // B is [N,K] row-major: Bs[k][n] = B[bn+n, k0+k]
            const int lk = tid & 15;
            const int n0 = tid >> 4;
            const int gk = k0 + lk;
            #pragma unroll
            for (int i = 0; i < 4; i++) {
                const int n = n0 + i * 16;
                const int gn = bn + n;
                float v = 0.f;
                if (gn < N && gk < K) v = Bm[(long long)gn * ldb + gk];
                Bs[lk][n] = v;
            }
        }
        __syncthreads();

        #pragma unroll
        for (int k = 0; k < 16; k++) {
            const float4 av = *reinterpret_cast<const float4*>(&As[k][ty * 4]);
            const float4 bv = *reinterpret_cast<const float4*>(&Bs[k][tx * 4]);
            const float a[4] = {av.x, av.y, av.z, av.w};
            const float b[4] = {bv.x, bv.y, bv.z, bv.w};
            #pragma unroll
            for (int i = 0; i < 4; i++)
                #pragma unroll
                for (int j = 0; j < 4; j++)
                    acc[i][j] = fmaf(a[i], b[j], acc[i][j]);
        }
        __syncthreads();
    }

    #pragma unroll
    for (int i = 0; i < 4; i++) {
        const int gm = bm + ty * 4 + i;
        if (gm >= M) continue;
        #pragma unroll
        for (int j = 0; j < 4; j++) {
            const int gn = bn + tx * 4 + j;
            if (gn >= N) continue;
            const long long idx = (long long)gm * ldc + gn;
            float v = acc[i][j];
            if (flags & F_ACCUM) v += C[idx];
            if (flags & F_RELU)  v = fmaxf(v, 0.f);
            C[idx] = v;
        }
    }
}

// sizes[side*256 + b] = count_nonzero(x_side[b, :])
__global__ void sizes_kernel(const int* __restrict__ x1, const int* __restrict__ x2,
                             int* __restrict__ sizes)
{
    const int b = blockIdx.x;
    const int side = blockIdx.y;
    const int* x = (side ? x2 : x1) + b * SEQ;
    const int nz = (x[threadIdx.x] != 0) ? 1 : 0;
    const unsigned long long bal = __ballot(nz);
    __shared__ int part[2];
    if ((threadIdx.x & 63) == 0) part[threadIdx.x >> 6] = __popcll(bal);
    __syncthreads();
    if (threadIdx.x == 0) sizes[side * BATCH + b] = part[0] + part[1];
}

// out[t, :] = emb[x[t], :] / ||emb[x[t], :]||_2   (one wave per token)
__global__ void gather_norm_kernel(const int* __restrict__ x, const float* __restrict__ emb,
                                   float* __restrict__ out)
{
    const int t = blockIdx.x;
    const int lane = threadIdx.x;
    const int tok = x[t];
    const float* row = emb + (long long)tok * EDIM;
    float v[5];
    float ss = 0.f;
    #pragma unroll
    for (int i = 0; i < 5; i++) {
        const int c = lane + i * 64;
        const float f = (c < EDIM) ? row[c] : 0.f;
        v[i] = f;
        ss += f * f;
    }
    #pragma unroll
    for (int o = 32; o > 0; o >>= 1) ss += __shfl_xor(ss, o);
    const float inv = rsqrtf(fmaxf(ss, 1e-12f));
    float* orow = out + (long long)t * EDIM;
    #pragma unroll
    for (int i = 0; i < 5; i++) {
        const int c = lane + i * 64;
        if (c < EDIM) orow[c] = v[i] * inv;
    }
}

// Row softmax over last dim (len 128), optional distance bias (|i-j|>=10).
__global__ void softmax_row_kernel(float* __restrict__ att, const float* __restrict__ bias_ptr,
                                   int use_bias)
{
    const int row = blockIdx.x;            // b*128 + i
    const int i = row & (SEQ - 1);
    const int lane = threadIdx.x;          // 64
    float* p = att + (long long)row * SEQ;
    float b0 = 0.f, b1 = 0.f;
    if (use_bias) {
        const float bias = bias_ptr[0];
        int d0 = i - lane;        d0 = d0 < 0 ? -d0 : d0;
        int d1 = i - (lane + 64); d1 = d1 < 0 ? -d1 : d1;
        b0 = (d0 >= 10) ? bias : 0.f;
        b1 = (d1 >= 10) ? bias : 0.f;
    }
    const float v0 = p[lane] + b0;
    const float v1 = p[lane + 64] + b1;
    float m = fmaxf(v0, v1);
    #pragma unroll
    for (int o = 32; o > 0; o >>= 1) m = fmaxf(m, __shfl_xor(m, o));
    const float e0 = __expf(v0 - m);
    const float e1 = __expf(v1 - m);
    float s = e0 + e1;
    #pragma unroll
    for (int o = 32; o > 0; o >>= 1) s += __shfl_xor(s, o);
    const float inv = 1.f / s;
    p[lane] = e0 * inv;
    p[lane + 64] = e1 * inv;
}

// Column softmax of sim (axis=1), written TRANSPOSED: smt[b,j,i] = softmax_i(sim[b,i,j])
__global__ void softmax_col_kernel(const float* __restrict__ sim, float* __restrict__ smt)
{
    const int cid = blockIdx.x;            // b*128 + j
    const int b = cid >> 7;
    const int j = cid & 127;
    const int lane = threadIdx.x;
    const float* p = sim + (long long)b * (SEQ * SEQ) + j;
    const float v0 = p[lane * SEQ];
    const float v1 = p[(lane + 64) * SEQ];
    float m = fmaxf(v0, v1);
    #pragma unroll
    for (int o = 32; o > 0; o >>= 1) m = fmaxf(m, __shfl_xor(m, o));
    const float e0 = __expf(v0 - m);
    const float e1 = __expf(v1 - m);
    float s = e0 + e1;
    #pragma unroll
    for (int o = 32; o > 0; o >>= 1) s += __shfl_xor(s, o);
    const float inv = 1.f / s;
    float* q = smt + (long long)b * (SEQ * SEQ) + (long long)j * SEQ;
    q[lane] = e0 * inv;
    q[lane + 64] = e1 * inv;
}

// Multiplicative mask: sim[b,i,j] = 0 where i>=size1[b] or j>=size2[b]
__global__ void mask_sim_kernel(float* __restrict__ sim, const int* __restrict__ sizes)
{
    const int idx = blockIdx.x * 256 + threadIdx.x;   // B*S*S total
    const int b = idx >> 14;
    const int i = (idx >> 7) & 127;
    const int j = idx & 127;
    if (i >= sizes[b] || j >= sizes[BATCH + b]) sim[idx] = 0.f;
}

// out[b,n] = sum_{s < sizes[b]} v[b,s,n], n in [0,400)
__global__ void pool_kernel(const float* __restrict__ v, const int* __restrict__ sizes,
                            float* __restrict__ out)
{
    const int b = blockIdx.x;
    const int sz = sizes[b];
    const float* p = v + (long long)b * SEQ * 400;
    for (int n = threadIdx.x; n < 400; n += blockDim.x) {
        float acc = 0.f;
        for (int s = 0; s < sz; s++) acc += p[s * 400 + n];
        out[b * 400 + n] = acc;
    }
}

// y[b,c] = relu(sum_k concat(v1s,v2s)[b,k] * w_agg[k,c]), K=800, C=3
__global__ void agg_kernel(const float* __restrict__ v1s, const float* __restrict__ v2s,
                           const float* __restrict__ w_agg, float* __restrict__ y)
{
    const int b = blockIdx.x;
    const int lane = threadIdx.x;   // 64
    float a0 = 0.f, a1 = 0.f, a2 = 0.f;
    for (int k = lane; k < 800; k += 64) {
        const float v = (k < 400) ? v1s[b * 400 + k] : v2s[b * 400 + k - 400];
        a0 = fmaf(v, w_agg[k * 3 + 0], a0);
        a1 = fmaf(v, w_agg[k * 3 + 1], a1);
        a2 = fmaf(v, w_agg[k * 3 + 2], a2);
    }
    #pragma unroll
    for (int o = 32; o > 0; o >>= 1) {
        a0 += __shfl_xor(a0, o);
        a1 += __shfl_xor(a1, o);
        a2 += __shfl_xor(a2, o);
    }
    if (lane == 0) {
        y[b * 3 + 0] = fmaxf(a0, 0.f);
        y[b * 3 + 1] = fmaxf(a1, 0.f);
        y[b * 3 + 2] = fmaxf(a2, 0.f);
    }
}

static inline void launch_gemm(hipStream_t st, bool bt, const float* A, const float* B,
                               float* C, int M, int N, int K, int lda, int ldb, int ldc,
                               long long sA, long long sB, long long sC, int batch, int flags)
{
    dim3 grid((N + 63) / 64, (M + 63) / 64, batch);
    if (bt)
        gemm_kernel<true><<<grid, 256, 0, st>>>(A, B, C, M, N, K, lda, ldb, ldc, sA, sB, sC, flags);
    else
        gemm_kernel<false><<<grid, 256, 0, st>>>(A, B, C, M, N, K, lda, ldb, ldc, sA, sB, sC, flags);
}

extern "C" void kernel_launch(void* const* d_in, const int* in_sizes, int n_in,
                              void* d_out, int out_size, void* d_ws, size_t ws_size,
                              hipStream_t stream)
{
    (void)in_sizes; (void)n_in; (void)out_size; (void)ws_size;
    const int*   x1         = (const int*)d_in[0];
    const int*   x2         = (const int*)d_in[1];
    const float* emb        = (const float*)d_in[2];
    const float* w_intra    = (const float*)d_in[3];
    const float* bias_intra = (const float*)d_in[4];
    const float* w_proj1    = (const float*)d_in[5];
    const float* w_proj2    = (const float*)d_in[6];
    const float* w_att      = (const float*)d_in[7];
    const float* w_cmp1     = (const float*)d_in[8];
    const float* w_cmp2     = (const float*)d_in[9];
    const float* w_agg      = (const float*)d_in[10];
    float* y  = (float*)d_out;
    float* ws = (float*)d_ws;

    // Workspace layout (floats). Total ~60.1M floats = ~230 MiB.
    float* X1CAT = ws;                        // [32768,400]: x1p | beta
    float* X2CAT = X1CAT + 13107200;          // [32768,400]: x2p | alpha
    float* EBUF  = X2CAT + 13107200;          // [32768,300]  (e per side; later F1 / V)
    float* FBUF  = EBUF + 9830400;            // [32768,300]  (intra f; later F2; V spills here)
    float* ATT   = FBUF + 9830400;            // [256,128,128] (intra att; later sim)
    float* XPB   = ATT + 4194304;             // [32768,300]  (xp per side; later smt)
    float* V1S   = XPB + 9830400;             // [256,400]
    float* V2S   = V1S + 102400;              // [256,400]
    int*   SIZES = (int*)(V2S + 102400);      // [2,256]

    sizes_kernel<<<dim3(BATCH, 2), 128, 0, stream>>>(x1, x2, SIZES);

    for (int side = 0; side < 2; side++) {
        const int*   x    = side ? x2 : x1;
        const float* wp   = side ? w_proj2 : w_proj1;
        float*       XCAT = side ? X2CAT : X1CAT;

        // e = l2norm(emb)[x]  -> EBUF [32768,300]
        gather_norm_kernel<<<BSTOK, 64, 0, stream>>>(x, emb, EBUF);
        // f = relu(e @ w_intra)  [32768,300]x[300,300]
        launch_gemm(stream, false, EBUF, w_intra, FBUF, BSTOK, EDIM, EDIM,
                    EDIM, EDIM, EDIM, 0, 0, 0, 1, F_RELU);
        // att[b] = f[b] @ f[b]^T  (batched NT, 128x128x300)
        launch_gemm(stream, true, FBUF, FBUF, ATT, SEQ, SEQ, EDIM,
                    EDIM, EDIM, SEQ, (long long)SEQ * EDIM, (long long)SEQ * EDIM,
                    (long long)SEQ * SEQ, BATCH, 0);
        // softmax rows + distance bias
        softmax_row_kernel<<<BSTOK, 64, 0, stream>>>(ATT, bias_intra, 1);
        // xp[b] = sm[b] @ e[b]  (batched NN, 128x300x128)
        launch_gemm(stream, false, ATT, EBUF, XPB, SEQ, EDIM, SEQ,
                    SEQ, EDIM, EDIM, (long long)SEQ * SEQ, (long long)SEQ * EDIM,
                    (long long)SEQ * EDIM, BATCH, 0);
        // xproj = relu(e @ wp[0:300] + xp @ wp[300:600]) -> XCAT cols 0:200 (ldc=400)
        launch_gemm(stream, false, EBUF, wp, XCAT, BSTOK, PDIM, EDIM,
                    EDIM, PDIM, 400, 0, 0, 0, 1, 0);
        launch_gemm(stream, false, XPB, wp + EDIM * PDIM, XCAT, BSTOK, PDIM, EDIM,
                    EDIM, PDIM, 400, 0, 0, 0, 1, F_RELU | F_ACCUM);
    }

    float* F1  = EBUF;
    float* F2  = FBUF;
    float* SIM = ATT;
    float* SMT = XPB;

    // f1 = relu(x1p @ w_att), f2 = relu(x2p @ w_att)   [32768,200]x[200,200]
    launch_gemm(stream, false, X1CAT, w_att, F1, BSTOK, PDIM, PDIM,
                400, PDIM, PDIM, 0, 0, 0, 1, F_RELU);
    launch_gemm(stream, false, X2CAT, w_att, F2, BSTOK, PDIM, PDIM,
                400, PDIM, PDIM, 0, 0, 0, 1, F_RELU);
    // sim[b] = f1[b] @ f2[b]^T  (batched NT, 128x128x200)
    launch_gemm(stream, true, F1, F2, SIM, SEQ, SEQ, PDIM,
                PDIM, PDIM, SEQ, (long long)SEQ * PDIM, (long long)SEQ * PDIM,
                (long long)SEQ * SEQ, BATCH, 0);
    // multiplicative sequence mask
    mask_sim_kernel<<<(BATCH * SEQ * SEQ) / 256, 256, 0, stream>>>(SIM, SIZES);
    // column softmax (axis=1), transposed -> SMT ; then row softmax (axis=2) in place
    softmax_col_kernel<<<BSTOK, 64, 0, stream>>>(SIM, SMT);
    softmax_row_kernel<<<BSTOK, 64, 0, stream>>>(SIM, bias_intra, 0);
    // beta[b]  = rowsm(sim)[b] @ x2p[b] -> X1CAT cols 200:400
    launch_gemm(stream, false, SIM, X2CAT, X1CAT + 200, SEQ, PDIM, SEQ,
                SEQ, 400, 400, (long long)SEQ * SEQ, (long long)SEQ * 400,
                (long long)SEQ * 400, BATCH, 0);
    // alpha[b] = colsm(sim)^T[b] @ x1p[b] -> X2CAT cols 200:400
    launch_gemm(stream, false, SMT, X1CAT, X2CAT + 200, SEQ, PDIM, SEQ,
                SEQ, 400, 400, (long long)SEQ * SEQ, (long long)SEQ * 400,
                (long long)SEQ * 400, BATCH, 0);

    float* V = EBUF;  // [32768,400], spans EBUF+FBUF region (free now)

    // v1 = relu([x1p|beta] @ w_cmp1); masked sum-pool over s
    launch_gemm(stream, false, X1CAT, w_cmp1, V, BSTOK, 400, 400,
                400, 400, 400, 0, 0, 0, 1, F_RELU);
    pool_kernel<<<BATCH, 256, 0, stream>>>(V, SIZES, V1S);
    // v2 = relu([x2p|alpha] @ w_cmp2); masked sum-pool
    launch_gemm(stream, false, X2CAT, w_cmp2, V, BSTOK, 400, 400,
                400, 400, 400, 0, 0, 0, 1, F_RELU);
    pool_kernel<<<BATCH, 256, 0, stream>>>(V, SIZES + BATCH, V2S);

    // y = relu(concat(v1s, v2s) @ w_agg)
    agg_kernel<<<BATCH, 64, 0, stream>>>(V1S, V2S, w_agg, y);
}